// Round 16
// baseline (79.989 us; speedup 1.0000x reference)
//
#include <hip/hip_runtime.h>
#include <stdint.h>

// FFM: B=4096, F=20 fields x S=500 feats, K=16.
// E2[b, i*336 + g*16 + k] = sum_s x[b,i*500+s]*v[g,i*500+s,k]  (g<20)
// E2[b, i*336 + 320]      = sum_s x[b,i*500+s]*w[i*500+s]      (linear partial)
// out[b] = sum_i E2[b,i,320] + sum_{i<j,k} E2[b,i*336+j*16+k]*E2[b,j*336+i*16+k]

#define NF 20
#define FS 500
#define TFEAT 10000
#define KD 16
#define NCOL 336        // 21 frags: 320 interaction cols + 16-col w block
#define NFRG 21
#define NB 4096
#define ROWE (NF * NCOL)  // 6720

typedef __bf16 bf16x8 __attribute__((ext_vector_type(8)));
typedef __bf16 bf16x2 __attribute__((ext_vector_type(2)));
typedef float  f32x4  __attribute__((ext_vector_type(4)));
typedef unsigned int u32x4 __attribute__((ext_vector_type(4)));

typedef __attribute__((address_space(1))) const void* as1cv;
typedef __attribute__((address_space(3))) void* as3v;

__device__ inline void gload_lds16(const void* g, void* l) {
  __builtin_amdgcn_global_load_lds((as1cv)g, (as3v)l, 16, 0, 0);
}

// ---------------- prep: VtS in STAGED order (unchanged, verified R9-R14).
// VtS[((i*16+t32)*21+q)*512 + l*8 + e] = B-panel value for row n=16q+(l>>2),
// kk = t32*32 + ((l&3)^((l>>3)&3))*8 + e.  n<320 -> v; n==320 -> w; else 0.
__global__ __launch_bounds__(256) void prep_vt(const float* __restrict__ v,
                                               const float* __restrict__ w,
                                               __bf16* __restrict__ VtS) {
  const int i = blockIdx.x / NFRG;
  const int q = blockIdx.x % NFRG;
  const int tdx = threadIdx.x;
  __shared__ float lv[FS * 17];
  if (q < NF) {  // panel for g=q: lv[s*17+k] = v[g, i*500+s, k]
    const int k = tdx & 15, sb = tdx >> 4;
    const float* vb = v + ((size_t)q * TFEAT + (size_t)i * FS) * KD;
    for (int it = 0; it < 32; ++it) {
      int s = it * 16 + sb;
      if (s < FS) lv[s * 17 + k] = vb[(size_t)s * KD + k];
    }
    __syncthreads();
  }
  const float* wf = w + (size_t)i * FS;
  __bf16* base = VtS + ((size_t)i * 16 * NFRG + q) * 512;
  for (int it = 0; it < 4; ++it) {
    int p = it * 256 + tdx;            // (t32,l) pair: 16*64 = 1024
    int t = p >> 6, l = p & 63;
    int r = l >> 2;                    // row within group (= k for q<20)
    int kk = t * 32 + (((l & 3) ^ ((l >> 3) & 3)) << 3);
    bf16x8 h;
#pragma unroll
    for (int e = 0; e < 8; ++e) {
      int s = kk + e;
      float val = 0.f;
      if (s < FS) {
        if (q < NF) val = lv[s * 17 + r];
        else if (r == 0) val = wf[s];
      }
      h[e] = (__bf16)val;
    }
    *(bf16x8*)(base + (size_t)t * (NFRG * 512) + l * 8) = h;
  }
}

// ---------------- K1: per-field GEMM. BM=64, BN=336, BK=32, 16 steps, 4 waves.
// RING-3 pipeline, ONE barrier per K-step:
//   compute(t) reads As/Bs slot t%3 (staged TWO periods ago);
//   R(t): issueB(t+2)->slot (t+2)%3; astore(t+1) (regs 1 period old);
//         aload(t+2) -> reg set (t+2)%3; s_waitcnt vmcnt(8) (retires only
//         period-old B(t+1)+A(t+1), leaves 8 fresh in flight); barrier.
// vmcnt never reaches 0 until t=14. LDS 75 KB -> 2 blocks/CU.
__global__ __launch_bounds__(256, 2) void k1_gemm(
    const float* __restrict__ x, const __bf16* __restrict__ VtS,
    __bf16* __restrict__ E2, int chunk_base, int tiles) {
  __shared__ __bf16 As[3][64][32];        // 12288 B, ring of K-steps
  __shared__ __bf16 Bs[3][NCOL * 32];     // 64512 B, ring of K-steps

  int bid = blockIdx.x;
  const int nwg = gridDim.x;
  if ((nwg & 7) == 0) {                   // bijective XCD swizzle
    int cpx = nwg >> 3;
    bid = (bid & 7) * cpx + (bid >> 3);
  }
  const int i  = bid / tiles;
  const int tb = bid % tiles;
  const int tid = threadIdx.x;
  const int lane = tid & 63, wid = tid >> 6;
  const int b0 = chunk_base + tb * 64;

  // A stage (per thread): row = tid>>2, 8 f32 cols at (tid&3)*8; XOR chunk
  const int arow = tid >> 2;
  const int ac8 = (tid & 3) * 8;
  const int apch = (tid & 3) ^ ((tid >> 3) & 3);
  const float* xrow = x + (size_t)(b0 + arow) * TFEAT + i * FS;
  const __bf16* VtSi = VtS + (size_t)i * 16 * NFRG * 512 + lane * 8;

  auto issueB = [&](int t, int slot) {
#pragma unroll
    for (int jj = 0; jj < 6; ++jj) {
      int q = wid + 4 * jj;
      if (q < NFRG)
        gload_lds16(VtSi + ((size_t)t * NFRG + q) * 512,
                    (void*)&Bs[slot][q * 512]);
    }
  };

  f32x4 aS0[2], aS1[2], aS2[2];           // three named reg sets (ring %3)
  auto aload = [&](int t, f32x4* r) {
    int kk = t * 32 + ac8;
    int c0 = kk > 496 ? 496 : kk;          // clamp: junk cols pair with zero B
    int c1 = kk + 4 > 496 ? 496 : kk + 4;
    r[0] = *(const f32x4*)(xrow + c0);
    r[1] = *(const f32x4*)(xrow + c1);
  };
  auto astore = [&](int slot, const f32x4* r) {
    bf16x8 h;
#pragma unroll
    for (int e = 0; e < 4; ++e) {
      h[e] = (__bf16)r[0][e]; h[4 + e] = (__bf16)r[1][e];
    }
    *(bf16x8*)(&As[slot][arow][apch * 8]) = h;
  };

  const int nfr = wid ? 5 : 6;
  const int Fbase = wid ? (1 + wid * 5) : 0;
  const int ar = lane & 15, akc = lane >> 4;

  f32x4 acc[4][6];
#pragma unroll
  for (int m = 0; m < 4; ++m)
#pragma unroll
    for (int nf = 0; nf < 6; ++nf) acc[m][nf] = (f32x4){0.f, 0.f, 0.f, 0.f};

  auto compute = [&](int slot) {
    bf16x8 bfr[6];
#pragma unroll
    for (int nf = 0; nf < 6; ++nf)
      if (nf < nfr) {
        int n_ = (Fbase + nf) * 16 + ar;
        int pc = akc ^ ((n_ >> 1) & 3);
        bfr[nf] = *(const bf16x8*)&Bs[slot][n_ * 32 + pc * 8];
      }
#pragma unroll
    for (int m = 0; m < 4; ++m) {
      int row = m * 16 + ar;
      int pch = akc ^ ((row >> 1) & 3);
      bf16x8 af = *(const bf16x8*)(&As[slot][row][pch * 8]);
#pragma unroll
      for (int nf = 0; nf < 6; ++nf)
        if (nf < nfr)
          acc[m][nf] = __builtin_amdgcn_mfma_f32_16x16x32_bf16(af, bfr[nf],
                                                               acc[m][nf], 0, 0, 0);
    }
  };

  // prologue: stage steps 0,1 (B0,A0,B1,A1 in FIFO); As[0] written; drain to 8.
  issueB(0, 0);
  aload(0, aS0);
  issueB(1, 1);
  aload(1, aS1);
  astore(0, aS0);                        // compiler waits A0, leaves B1 in flight
  __builtin_amdgcn_sched_barrier(0);
  asm volatile("s_waitcnt vmcnt(8) lgkmcnt(0)" ::: "memory");  // retire B0+A0
  __builtin_amdgcn_s_barrier();

#pragma unroll
  for (int t = 0; t < 16; ++t) {
    compute(t % 3);
    if (t < 15) {
      __builtin_amdgcn_sched_barrier(0);
      if (t < 14) issueB(t + 2, (t + 2) % 3);
      {  // astore(t+1) from reg set (t+1)%3 (loads 1 period old)
        const int s1 = (t + 1) % 3;
        astore(s1, s1 == 0 ? aS0 : (s1 == 1 ? aS1 : aS2));
      }
      if (t < 14) {  // aload(t+2) into reg set (t+2)%3 (newest)
        const int s2 = (t + 2) % 3;
        aload(t + 2, s2 == 0 ? aS0 : (s2 == 1 ? aS1 : aS2));
      }
      __builtin_amdgcn_sched_barrier(0);
      if (t < 14)
        asm volatile("s_waitcnt vmcnt(8) lgkmcnt(0)" ::: "memory");  // counted
      else
        asm volatile("s_waitcnt vmcnt(0) lgkmcnt(0)" ::: "memory");  // tail
      __builtin_amdgcn_s_barrier();
    }
  }

  // epilogue: C/D layout col=lane&15, row=(lane>>4)*4+r
  const int lr4 = akc * 4, lcol = lane & 15;
#pragma unroll
  for (int m = 0; m < 4; ++m)
#pragma unroll
    for (int nf = 0; nf < 6; ++nf)
      if (nf < nfr) {
        int n = (Fbase + nf) * 16 + lcol;
#pragma unroll
        for (int r = 0; r < 4; ++r) {
          int bl = tb * 64 + m * 16 + lr4 + r;
          E2[(size_t)bl * ROWE + i * NCOL + n] = (__bf16)acc[m][nf][r];
        }
      }
}

// ---------------- K2: pair + linear reduction, 1 wave per batch row
__global__ __launch_bounds__(256) void k2_pair(
    const __bf16* __restrict__ E2, float* __restrict__ out, int chunk_base) {
  __shared__ __align__(16) unsigned shw[4][3360];  // 13440 B per wave
  const int tid = threadIdx.x, lane = tid & 63, wid = tid >> 6;
  const int bl = blockIdx.x * 4 + wid;
  const unsigned* src = (const unsigned*)(E2 + (size_t)bl * ROWE);
  for (int it = 0; it < 14; ++it) {
    int idx = it * 64 + lane;             // 16B units; 840 total
    if (idx < 840) {
      u32x4 val = *(const u32x4*)(src + (size_t)idx * 4);
      *(u32x4*)&shw[wid][idx * 4] = val;
    }
  }
  __syncthreads();
  const __bf16* sh = (const __bf16*)shw[wid];
  const int k = lane & 15, g = lane >> 4;
  float sum = 0.f;
  for (int i = g; i < NF; i += 4)
    for (int j = i + 1; j < NF; ++j)
      sum += (float)sh[i * NCOL + j * 16 + k] * (float)sh[j * NCOL + i * 16 + k];
  if (lane < NF) sum += (float)sh[lane * NCOL + 320];   // linear term
#pragma unroll
  for (int off = 32; off; off >>= 1) sum += __shfl_xor(sum, off);
  if (lane == 0) out[chunk_base + bl] = sum;
}

extern "C" void kernel_launch(void* const* d_in, const int* in_sizes, int n_in,
                              void* d_out, int out_size, void* d_ws, size_t ws_size,
                              hipStream_t stream) {
  const float* x = (const float*)d_in[0];
  const float* w = (const float*)d_in[1];
  const float* v = (const float*)d_in[2];
  float* out = (float*)d_out;
  char* ws = (char*)d_ws;

  const size_t vt_bytes = (size_t)NF * 16 * NFRG * 512 * 2;   // 6,881,280
  __bf16* VtS = (__bf16*)ws;
  __bf16* E2 = (__bf16*)(ws + vt_bytes);

  size_t eavail = (ws_size > vt_bytes) ? ws_size - vt_bytes : 0;
  int Bc = NB;
  while (Bc > 64 && (size_t)Bc * ROWE * 2 > eavail) Bc >>= 1;

  prep_vt<<<NF * NFRG, 256, 0, stream>>>(v, w, VtS);
  for (int cb = 0; cb < NB; cb += Bc) {
    int tiles = Bc / 64;
    k1_gemm<<<NF * tiles, 256, 0, stream>>>(x, VtS, E2, cb, tiles);
    k2_pair<<<Bc / 4, 256, 0, stream>>>(E2, out, cb);
  }
}